// Round 17
// baseline (138.999 us; speedup 1.0000x reference)
//
#include <hip/hip_runtime.h>
#include <hip/hip_bf16.h>

static constexpr int KC   = 9;    // kernel bins
static constexpr int CIN  = 32;   // input channels
static constexpr int CA   = 24;   // branch-a out channels
static constexpr int CB   = 8;    // branch-b out channels
static constexpr int COUT = 32;   // CA + CB
static constexpr int KCC  = KC * CIN;       // 288
static constexpr int SPP  = 2 * KCC;        // 576 bf16 S entries per point

// ---------------------------------------------------------------------------
// Prep: CSR row pointer + packed (i,q) key + per-edge importance + W pack.
// keym[e] = (nidx[e] << 4) | nkidx[e]   (nidx < 2^27, q < 16)
// ---------------------------------------------------------------------------
__global__ void prep(const int* __restrict__ oidx, const int* __restrict__ nidx,
                     const int* __restrict__ nkidx,
                     const float* __restrict__ importance,
                     const float* __restrict__ Wa, const float* __restrict__ Wb,
                     int* __restrict__ rp, float* __restrict__ imp_e,
                     int* __restrict__ keym, float* __restrict__ Wc,
                     int E, int nout) {
    int e = blockIdx.x * blockDim.x + threadIdx.x;
    if (e < E) {
        int cur  = oidx[e];
        int prev = (e == 0) ? -1 : oidx[e - 1];
        for (int id = prev + 1; id <= cur; ++id) rp[id] = e;
        if (e == E - 1) {
            for (int id = cur + 1; id <= nout; ++id) rp[id] = E;
        }
        int i = nidx[e];
        imp_e[e] = importance[i];
        keym[e]  = (i << 4) | nkidx[e];
        if (e < KCC * COUT) {
            int f  = e & (COUT - 1);
            int kc = e >> 5;
            Wc[e] = (f < CA) ? Wa[kc * CA + f] : Wb[kc * CB + (f - CA)];
        }
    }
}

// uniform-q conditional add (round-11's measured-best linear scalar chain)
#define ACC_ADD(Q, V)                              \
    do {                                           \
        if      ((Q) == 0) acc[0] += (V);          \
        else if ((Q) == 1) acc[1] += (V);          \
        else if ((Q) == 2) acc[2] += (V);          \
        else if ((Q) == 3) acc[3] += (V);          \
        else if ((Q) == 4) acc[4] += (V);          \
        else if ((Q) == 5) acc[5] += (V);          \
        else if ((Q) == 6) acc[6] += (V);          \
        else if ((Q) == 7) acc[7] += (V);          \
        else               acc[8] += (V);          \
    } while (0)

__device__ __forceinline__ float readlane_f(float v, int l) {
    return __uint_as_float(__builtin_amdgcn_readlane(__float_as_uint(v), l));
}

// per-edge body: fz = f * o (SALU-zeroed valid flag), v = fz * (h ? m : 1)
#define EDGE(J)                                                        \
    do {                                                               \
        float fz = f##J * o##J;                                        \
        float mm = h ? m##J : 1.0f;   /* v_cndmask inline1.0 + sgpr */ \
        ACC_ADD(q##J, fz * mm);                                        \
    } while (0)

// ---------------------------------------------------------------------------
// Kernel A: packed-key vector-path metadata, 8-edge groups, SALU masking.
// Grid-stride wave per point (self-balancing). Per 8 edges: 2 vector loads
// (keym, imp_e via lane&7), 16 readlanes -> SGPRs, i/q extracted on SALU,
// clamp-zero flags as SALU float selects (no branches). 8 independent
// feats row gathers in flight. accImp accumulated per-lane (own edge) and
// reduced with 3 shfl_xor at flush. bf16 S flush stores.
// ---------------------------------------------------------------------------
__global__ __launch_bounds__(256) void accum_z(
    const float* __restrict__ feats, const float* __restrict__ imp_e,
    const int* __restrict__ keym, const int* __restrict__ rp,
    __hip_bfloat16* __restrict__ S, float* __restrict__ impAcc, int nout)
{
    const int lane = threadIdx.x & 63;
    const int c    = lane & 31;
    const int h    = lane >> 5;
    const int l8   = lane & 7;
    int gw = (blockIdx.x * 256 + threadIdx.x) >> 6;
    gw = __builtin_amdgcn_readfirstlane(gw);          // uniform wave id
    const int NW = (gridDim.x * 256) >> 6;

    for (int n = gw; n < nout; n += NW) {
        const int start = rp[n];                      // uniform
        const int end   = rp[n + 1];                  // uniform

        float acc[KC];
#pragma unroll
        for (int k = 0; k < KC; ++k) acc[k] = 0.f;
        float accImpL = 0.f;                          // per-lane partial

        for (int e = start; e < end; e += 8) {
            // per-lane metadata edge (clamped); 32B-line vector loads
            int em = e + l8;
            if (em > end - 1) em = end - 1;
            int   keyv = keym[em];
            float mv   = imp_e[em];

            // per-lane importance accumulation (own slot only, zero if clamped)
            accImpL += (e + l8 < end) ? mv : 0.f;

            // move to SGPRs; extract i/q on SALU
            int k0 = __builtin_amdgcn_readlane(keyv, 0);
            int k1 = __builtin_amdgcn_readlane(keyv, 1);
            int k2 = __builtin_amdgcn_readlane(keyv, 2);
            int k3 = __builtin_amdgcn_readlane(keyv, 3);
            int k4 = __builtin_amdgcn_readlane(keyv, 4);
            int k5 = __builtin_amdgcn_readlane(keyv, 5);
            int k6 = __builtin_amdgcn_readlane(keyv, 6);
            int k7 = __builtin_amdgcn_readlane(keyv, 7);
            float m0 = readlane_f(mv, 0), m1 = readlane_f(mv, 1);
            float m2 = readlane_f(mv, 2), m3 = readlane_f(mv, 3);
            float m4 = readlane_f(mv, 4), m5 = readlane_f(mv, 5);
            float m6 = readlane_f(mv, 6), m7 = readlane_f(mv, 7);
            int i0 = k0 >> 4, q0 = k0 & 15;
            int i1 = k1 >> 4, q1 = k1 & 15;
            int i2 = k2 >> 4, q2 = k2 & 15;
            int i3 = k3 >> 4, q3 = k3 & 15;
            int i4 = k4 >> 4, q4 = k4 & 15;
            int i5 = k5 >> 4, q5 = k5 & 15;
            int i6 = k6 >> 4, q6 = k6 & 15;
            int i7 = k7 >> 4, q7 = k7 & 15;

            // SALU validity flags (s_cselect float constants; no branches)
            const float o0 = 1.0f;
            float o1 = (e + 1 < end) ? 1.0f : 0.0f;
            float o2 = (e + 2 < end) ? 1.0f : 0.0f;
            float o3 = (e + 3 < end) ? 1.0f : 0.0f;
            float o4 = (e + 4 < end) ? 1.0f : 0.0f;
            float o5 = (e + 5 < end) ? 1.0f : 0.0f;
            float o6 = (e + 6 < end) ? 1.0f : 0.0f;
            float o7 = (e + 7 < end) ? 1.0f : 0.0f;

            // 8 independent coalesced 128B row gathers in flight
            float f0 = feats[(size_t)i0 * CIN + c];
            float f1 = feats[(size_t)i1 * CIN + c];
            float f2 = feats[(size_t)i2 * CIN + c];
            float f3 = feats[(size_t)i3 * CIN + c];
            float f4 = feats[(size_t)i4 * CIN + c];
            float f5 = feats[(size_t)i5 * CIN + c];
            float f6 = feats[(size_t)i6 * CIN + c];
            float f7 = feats[(size_t)i7 * CIN + c];

            EDGE(0); EDGE(1); EDGE(2); EDGE(3);
            EDGE(4); EDGE(5); EDGE(6); EDGE(7);
        }

        // reduce accImp over the 8 lane-slots (all lanes active, uniform loop)
        float impTot = accImpL;
        impTot += __shfl_xor(impTot, 1, 64);
        impTot += __shfl_xor(impTot, 2, 64);
        impTot += __shfl_xor(impTot, 4, 64);

        // flush: one wave-wide bf16 store per k (h selects Sa/Sb region)
        __hip_bfloat16* Sp = S + (size_t)n * SPP + h * KCC + c;
#pragma unroll
        for (int k = 0; k < KC; ++k) Sp[k * CIN] = __float2bfloat16(acc[k]);
        if (lane == 0) impAcc[n] = impTot;
    }
}
#undef EDGE
#undef ACC_ADD

// ---------------------------------------------------------------------------
// Kernel B: lane-per-point epilogue, bf16 S input. 128-thread blocks for
// finer CU balancing (2x blocks). W wave-uniform -> s_load through K$.
// ---------------------------------------------------------------------------
__global__ __launch_bounds__(128) void epilogue_g(
    const __hip_bfloat16* __restrict__ S, const float* __restrict__ impAcc,
    const float* __restrict__ Wc, const float* __restrict__ ba,
    const float* __restrict__ bb,
    float* __restrict__ outf, float* __restrict__ outimp, int nout)
{
    const int gtid   = blockIdx.x * 128 + threadIdx.x;
    const bool valid = (gtid < nout);
    const int n      = valid ? gtid : (nout - 1);

    const unsigned short* Sp =
        reinterpret_cast<const unsigned short*>(S + (size_t)n * SPP);

    float acc[COUT];
#pragma unroll
    for (int j = 0; j < COUT; ++j) acc[j] = 0.f;

    for (int t = 0; t < KCC; t += 8) {
        uint4 ua = *reinterpret_cast<const uint4*>(Sp + t);
        uint4 ub = *reinterpret_cast<const uint4*>(Sp + KCC + t);
        unsigned int uaw[4] = {ua.x, ua.y, ua.z, ua.w};
        unsigned int ubw[4] = {ub.x, ub.y, ub.z, ub.w};
        float sav[8], sbv[8];
#pragma unroll
        for (int p = 0; p < 4; ++p) {
            sav[2 * p]     = __uint_as_float(uaw[p] << 16);
            sav[2 * p + 1] = __uint_as_float(uaw[p] & 0xffff0000u);
            sbv[2 * p]     = __uint_as_float(ubw[p] << 16);
            sbv[2 * p + 1] = __uint_as_float(ubw[p] & 0xffff0000u);
        }
#pragma unroll
        for (int u = 0; u < 8; ++u) {
            const float* w = Wc + (t + u) * COUT;   // wave-uniform -> s_load
#pragma unroll
            for (int j = 0; j < CA; ++j) acc[j] = fmaf(sav[u], w[j], acc[j]);
#pragma unroll
            for (int j = 0; j < CB; ++j)
                acc[CA + j] = fmaf(sbv[u], w[CA + j], acc[CA + j]);
        }
    }

    float impTot = impAcc[n];
    float denom  = impTot > 0.f ? impTot : 1.f;

    if (valid) {
        float res[COUT];
#pragma unroll
        for (int j = 0; j < CA; ++j) res[j] = fmaxf(acc[j] + ba[j], 0.f);
#pragma unroll
        for (int j = 0; j < CB; ++j)
            res[CA + j] = fmaxf(acc[CA + j] / denom + bb[j], 0.f);
        float4* op = reinterpret_cast<float4*>(outf + (size_t)n * COUT);
#pragma unroll
        for (int j4 = 0; j4 < 8; ++j4)
            op[j4] = make_float4(res[4 * j4], res[4 * j4 + 1],
                                 res[4 * j4 + 2], res[4 * j4 + 3]);
        outimp[n] = impTot;
    }
}

// ===========================================================================
// Fallback (round-6 fused kernel) if ws can't hold the scratch.
// ===========================================================================
static constexpr int WSTR = KC * CIN + 4;
static constexpr int PPB = 16;
static constexpr int TPB = 512;
static constexpr int NHW = TPB / 32;

__global__ void build_rowptr_fb(const int* __restrict__ oidx, int* __restrict__ rp,
                                int E, int nout) {
    int e = blockIdx.x * blockDim.x + threadIdx.x;
    if (e >= E) return;
    int cur  = oidx[e];
    int prev = (e == 0) ? -1 : oidx[e - 1];
    for (int id = prev + 1; id <= cur; ++id) rp[id] = e;
    if (e == E - 1) {
        for (int id = cur + 1; id <= nout; ++id) rp[id] = E;
    }
}

__global__ void pack_weights_fkc(const float* __restrict__ Wa,
                                 const float* __restrict__ Wb,
                                 float* __restrict__ Wt) {
    int t = blockIdx.x * blockDim.x + threadIdx.x;
    if (t >= COUT * KC * CIN) return;
    int f = t / (KC * CIN);
    int r = t % (KC * CIN);
    Wt[t] = (f < CA) ? Wa[r * CA + f] : Wb[r * CB + (f - CA)];
}

__global__ __launch_bounds__(TPB) void fused_block(
    const float* __restrict__ feats, const float* __restrict__ importance,
    const float* __restrict__ Wt, const float* __restrict__ ba,
    const float* __restrict__ bb,
    const int* __restrict__ nidx, const int* __restrict__ nkidx,
    const int* __restrict__ noidx, const int* __restrict__ rp,
    float* __restrict__ outf, float* __restrict__ outimp, int nout)
{
    __shared__ __align__(16) float sW[COUT * WSTR];
    __shared__ __align__(16) float sS[PPB][2][KC * CIN];
    __shared__ float sImp[PPB];

    const int tid = threadIdx.x;
    const int hw  = tid >> 5;
    const int c   = tid & 31;
    const int p0  = blockIdx.x * PPB;

    {
        float* pS = &sS[0][0][0];
        for (int i = tid; i < PPB * 2 * KC * CIN; i += TPB) pS[i] = 0.f;
        for (int i = tid; i < COUT * KC * CIN; i += TPB) {
            int f = i / (KC * CIN);
            int r = i % (KC * CIN);
            sW[f * WSTR + r] = Wt[i];
        }
        if (tid < PPB) sImp[tid] = 0.f;
    }
    __syncthreads();

    const int pend   = (p0 + PPB < nout) ? (p0 + PPB) : nout;
    const int estart = rp[p0];
    const int eend   = rp[pend];
    const int cnt    = eend - estart;
    const int per    = (cnt + NHW - 1) / NHW;
    int a = estart + hw * per;
    int b = a + per; if (b > eend) b = eend;

    float* S0 = &sS[0][0][0];
    for (int e = a; e < b; ++e) {
        int   n0 = noidx[e], i0 = nidx[e], q0 = nkidx[e];
        float m0 = importance[i0];
        float f0 = feats[(size_t)i0 * CIN + c];
        float* bp = S0 + (n0 - p0) * (2 * KC * CIN) + q0 * CIN + c;
        atomicAdd(bp, f0);
        atomicAdd(bp + KC * CIN, f0 * m0);
        if (c == 0) atomicAdd(&sImp[n0 - p0], m0);
    }
    __syncthreads();

    const int wave = tid >> 6;
    const int lane = tid & 63;
    const int f    = lane & 31;
    const int h    = lane >> 5;
#pragma unroll
    for (int rep = 0; rep < 2; ++rep) {
        const int slot = wave * 2 + rep;
        const int n    = p0 + slot;
        if (n >= nout) break;
        float impTot = sImp[slot];
        float denom  = impTot > 0.f ? impTot : 1.f;
        const float* Sbase = &sS[slot][(f < CA) ? 0 : 1][0];
        const float* Wbase = sW + f * WSTR;
        float acc = 0.f;
#pragma unroll
        for (int k = 0; k < KC; ++k) {
            int off = k * CIN + h * 16;
#pragma unroll
            for (int j = 0; j < 16; ++j) acc = fmaf(Sbase[off + j], Wbase[off + j], acc);
        }
        float tot = acc + __shfl_xor(acc, 32, 64);
        if (h == 0) {
            float res = (f < CA) ? (tot + ba[f]) : (tot / denom + bb[f - CA]);
            outf[(size_t)n * COUT + f] = fmaxf(res, 0.f);
        }
        if (lane == 0) outimp[n] = impTot;
    }
}

// ---------------------------------------------------------------------------
extern "C" void kernel_launch(void* const* d_in, const int* in_sizes, int n_in,
                              void* d_out, int out_size, void* d_ws, size_t ws_size,
                              hipStream_t stream) {
    const float* feats      = (const float*)d_in[0];
    const float* importance = (const float*)d_in[1];
    const float* Wa         = (const float*)d_in[2];
    const float* ba         = (const float*)d_in[3];
    const float* Wb         = (const float*)d_in[4];
    const float* bb         = (const float*)d_in[5];
    const int*   nidx       = (const int*)d_in[6];
    const int*   nkidx      = (const int*)d_in[7];
    const int*   noidx      = (const int*)d_in[8];

    const int E    = in_sizes[6];
    const int nout = out_size / (COUT + 1);

    float* outf   = (float*)d_out;
    float* outimp = outf + (size_t)nout * COUT;

    // ws: S bf16 [nout*576] | impAcc | Wc | rp | imp_e [E] | keym [E]
    const size_t off_imp = ((size_t)nout * SPP * sizeof(__hip_bfloat16) + 255) & ~(size_t)255;
    const size_t off_wc  = (off_imp + (size_t)nout * sizeof(float) + 255) & ~(size_t)255;
    const size_t off_rp  = (off_wc + (size_t)KCC * COUT * sizeof(float) + 255) & ~(size_t)255;
    const size_t off_ie  = (off_rp + (size_t)(nout + 1) * sizeof(int) + 255) & ~(size_t)255;
    const size_t off_km  = (off_ie + (size_t)E * sizeof(float) + 255) & ~(size_t)255;
    const size_t need    = off_km + (size_t)E * sizeof(int);

    if (ws_size >= need) {
        __hip_bfloat16* S = (__hip_bfloat16*)d_ws;
        float* impAcc = (float*)((char*)d_ws + off_imp);
        float* Wc     = (float*)((char*)d_ws + off_wc);
        int*   rp     = (int*)((char*)d_ws + off_rp);
        float* imp_e  = (float*)((char*)d_ws + off_ie);
        int*   keym   = (int*)((char*)d_ws + off_km);

        prep<<<(E + 255) / 256, 256, 0, stream>>>(
            noidx, nidx, nkidx, importance, Wa, Wb, rp, imp_e, keym, Wc, E, nout);
        accum_z<<<2048, 256, 0, stream>>>(
            feats, imp_e, keym, rp, S, impAcc, nout);
        epilogue_g<<<(nout + 127) / 128, 128, 0, stream>>>(
            S, impAcc, Wc, ba, bb, outf, outimp, nout);
    } else {
        int*   rp = (int*)d_ws;
        size_t rp_bytes = ((size_t)(nout + 1) * sizeof(int) + 255) & ~(size_t)255;
        float* Wt = (float*)((char*)d_ws + rp_bytes);

        build_rowptr_fb<<<(E + 255) / 256, 256, 0, stream>>>(noidx, rp, E, nout);
        pack_weights_fkc<<<(COUT * KC * CIN + 255) / 256, 256, 0, stream>>>(Wa, Wb, Wt);
        fused_block<<<(nout + PPB - 1) / PPB, TPB, 0, stream>>>(
            feats, importance, Wt, ba, bb, nidx, nkidx, noidx, rp,
            outf, outimp, nout);
    }
}

// Round 18
// 136.621 us; speedup vs baseline: 1.0174x; 1.0174x over previous
//
#include <hip/hip_runtime.h>
#include <hip/hip_bf16.h>

static constexpr int KC   = 9;    // kernel bins
static constexpr int CIN  = 32;   // input channels
static constexpr int CA   = 24;   // branch-a out channels
static constexpr int CB   = 8;    // branch-b out channels
static constexpr int COUT = 32;   // CA + CB
static constexpr int KCC  = KC * CIN;       // 288
static constexpr int SPP  = 2 * KCC;        // 576 bf16 S entries per point

// ---------------------------------------------------------------------------
// Prep: CSR row pointer + packed (i,q) key + per-edge importance + W pack.
// keym[e] = (nidx[e] << 4) | nkidx[e]   (nidx < 2^27, q < 16)
// ---------------------------------------------------------------------------
__global__ void prep(const int* __restrict__ oidx, const int* __restrict__ nidx,
                     const int* __restrict__ nkidx,
                     const float* __restrict__ importance,
                     const float* __restrict__ Wa, const float* __restrict__ Wb,
                     int* __restrict__ rp, float* __restrict__ imp_e,
                     int* __restrict__ keym, float* __restrict__ Wc,
                     int E, int nout) {
    int e = blockIdx.x * blockDim.x + threadIdx.x;
    if (e < E) {
        int cur  = oidx[e];
        int prev = (e == 0) ? -1 : oidx[e - 1];
        for (int id = prev + 1; id <= cur; ++id) rp[id] = e;
        if (e == E - 1) {
            for (int id = cur + 1; id <= nout; ++id) rp[id] = E;
        }
        int i = nidx[e];
        imp_e[e] = importance[i];
        keym[e]  = (i << 4) | nkidx[e];
        if (e < KCC * COUT) {
            int f  = e & (COUT - 1);
            int kc = e >> 5;
            Wc[e] = (f < CA) ? Wa[kc * CA + f] : Wb[kc * CB + (f - CA)];
        }
    }
}

// uniform-q conditional add (round-11's measured-best linear scalar chain)
#define ACC_ADD(Q, V)                              \
    do {                                           \
        if      ((Q) == 0) acc[0] += (V);          \
        else if ((Q) == 1) acc[1] += (V);          \
        else if ((Q) == 2) acc[2] += (V);          \
        else if ((Q) == 3) acc[3] += (V);          \
        else if ((Q) == 4) acc[4] += (V);          \
        else if ((Q) == 5) acc[5] += (V);          \
        else if ((Q) == 6) acc[6] += (V);          \
        else if ((Q) == 7) acc[7] += (V);          \
        else               acc[8] += (V);          \
    } while (0)

__device__ __forceinline__ float readlane_f(float v, int l) {
    return __uint_as_float(__builtin_amdgcn_readlane(__float_as_uint(v), l));
}

// per-edge body: fz = f * o (SALU-zeroed valid flag), v = fz * (h ? m : 1)
#define EDGE(J)                                                        \
    do {                                                               \
        float fz = f##J * o##J;                                        \
        float mm = h ? m##J : 1.0f;   /* v_cndmask inline1.0 + sgpr */ \
        ACC_ADD(q##J, fz * mm);                                        \
    } while (0)

// ---------------------------------------------------------------------------
// Kernel A (round-16 winner): packed-key vector-path metadata, 8-edge
// groups, SALU masking. Grid-stride wave per point (self-balancing).
// Per 8 edges: 2 vector loads (keym, imp_e via lane&7), 16 readlanes ->
// SGPRs, i/q extracted on SALU, clamp-zero flags as SALU float selects.
// 8 independent feats row gathers in flight. bf16 S flush stores.
// ---------------------------------------------------------------------------
__global__ __launch_bounds__(256) void accum_z(
    const float* __restrict__ feats, const float* __restrict__ imp_e,
    const int* __restrict__ keym, const int* __restrict__ rp,
    __hip_bfloat16* __restrict__ S, float* __restrict__ impAcc, int nout)
{
    const int lane = threadIdx.x & 63;
    const int c    = lane & 31;
    const int h    = lane >> 5;
    const int l8   = lane & 7;
    int gw = (blockIdx.x * 256 + threadIdx.x) >> 6;
    gw = __builtin_amdgcn_readfirstlane(gw);          // uniform wave id
    const int NW = (gridDim.x * 256) >> 6;

    for (int n = gw; n < nout; n += NW) {
        const int start = rp[n];                      // uniform
        const int end   = rp[n + 1];                  // uniform

        float acc[KC];
#pragma unroll
        for (int k = 0; k < KC; ++k) acc[k] = 0.f;
        float accImpL = 0.f;                          // per-lane partial

        for (int e = start; e < end; e += 8) {
            // per-lane metadata edge (clamped); 32B-line vector loads
            int em = e + l8;
            if (em > end - 1) em = end - 1;
            int   keyv = keym[em];
            float mv   = imp_e[em];

            // per-lane importance accumulation (own slot, zero if clamped)
            accImpL += (e + l8 < end) ? mv : 0.f;

            // move to SGPRs; extract i/q on SALU
            int k0 = __builtin_amdgcn_readlane(keyv, 0);
            int k1 = __builtin_amdgcn_readlane(keyv, 1);
            int k2 = __builtin_amdgcn_readlane(keyv, 2);
            int k3 = __builtin_amdgcn_readlane(keyv, 3);
            int k4 = __builtin_amdgcn_readlane(keyv, 4);
            int k5 = __builtin_amdgcn_readlane(keyv, 5);
            int k6 = __builtin_amdgcn_readlane(keyv, 6);
            int k7 = __builtin_amdgcn_readlane(keyv, 7);
            float m0 = readlane_f(mv, 0), m1 = readlane_f(mv, 1);
            float m2 = readlane_f(mv, 2), m3 = readlane_f(mv, 3);
            float m4 = readlane_f(mv, 4), m5 = readlane_f(mv, 5);
            float m6 = readlane_f(mv, 6), m7 = readlane_f(mv, 7);
            int i0 = k0 >> 4, q0 = k0 & 15;
            int i1 = k1 >> 4, q1 = k1 & 15;
            int i2 = k2 >> 4, q2 = k2 & 15;
            int i3 = k3 >> 4, q3 = k3 & 15;
            int i4 = k4 >> 4, q4 = k4 & 15;
            int i5 = k5 >> 4, q5 = k5 & 15;
            int i6 = k6 >> 4, q6 = k6 & 15;
            int i7 = k7 >> 4, q7 = k7 & 15;

            // SALU validity flags (s_cselect float constants; no branches)
            const float o0 = 1.0f;
            float o1 = (e + 1 < end) ? 1.0f : 0.0f;
            float o2 = (e + 2 < end) ? 1.0f : 0.0f;
            float o3 = (e + 3 < end) ? 1.0f : 0.0f;
            float o4 = (e + 4 < end) ? 1.0f : 0.0f;
            float o5 = (e + 5 < end) ? 1.0f : 0.0f;
            float o6 = (e + 6 < end) ? 1.0f : 0.0f;
            float o7 = (e + 7 < end) ? 1.0f : 0.0f;

            // 8 independent coalesced 128B row gathers in flight
            float f0 = feats[(size_t)i0 * CIN + c];
            float f1 = feats[(size_t)i1 * CIN + c];
            float f2 = feats[(size_t)i2 * CIN + c];
            float f3 = feats[(size_t)i3 * CIN + c];
            float f4 = feats[(size_t)i4 * CIN + c];
            float f5 = feats[(size_t)i5 * CIN + c];
            float f6 = feats[(size_t)i6 * CIN + c];
            float f7 = feats[(size_t)i7 * CIN + c];

            EDGE(0); EDGE(1); EDGE(2); EDGE(3);
            EDGE(4); EDGE(5); EDGE(6); EDGE(7);
        }

        // reduce accImp over the 8 lane-slots
        float impTot = accImpL;
        impTot += __shfl_xor(impTot, 1, 64);
        impTot += __shfl_xor(impTot, 2, 64);
        impTot += __shfl_xor(impTot, 4, 64);

        // flush: one wave-wide bf16 store per k (h selects Sa/Sb region)
        __hip_bfloat16* Sp = S + (size_t)n * SPP + h * KCC + c;
#pragma unroll
        for (int k = 0; k < KC; ++k) Sp[k * CIN] = __float2bfloat16(acc[k]);
        if (lane == 0) impAcc[n] = impTot;
    }
}
#undef EDGE
#undef ACC_ADD

// ---------------------------------------------------------------------------
// Kernel B (round-15 winner, 256 threads): lane-per-point epilogue, bf16 S.
// W addresses wave-uniform -> s_load through K$; S per-lane row stream.
// ---------------------------------------------------------------------------
__global__ __launch_bounds__(256) void epilogue_g(
    const __hip_bfloat16* __restrict__ S, const float* __restrict__ impAcc,
    const float* __restrict__ Wc, const float* __restrict__ ba,
    const float* __restrict__ bb,
    float* __restrict__ outf, float* __restrict__ outimp, int nout)
{
    const int gtid   = blockIdx.x * 256 + threadIdx.x;
    const bool valid = (gtid < nout);
    const int n      = valid ? gtid : (nout - 1);

    const unsigned short* Sp =
        reinterpret_cast<const unsigned short*>(S + (size_t)n * SPP);

    float acc[COUT];
#pragma unroll
    for (int j = 0; j < COUT; ++j) acc[j] = 0.f;

    for (int t = 0; t < KCC; t += 8) {
        uint4 ua = *reinterpret_cast<const uint4*>(Sp + t);
        uint4 ub = *reinterpret_cast<const uint4*>(Sp + KCC + t);
        unsigned int uaw[4] = {ua.x, ua.y, ua.z, ua.w};
        unsigned int ubw[4] = {ub.x, ub.y, ub.z, ub.w};
        float sav[8], sbv[8];
#pragma unroll
        for (int p = 0; p < 4; ++p) {
            sav[2 * p]     = __uint_as_float(uaw[p] << 16);
            sav[2 * p + 1] = __uint_as_float(uaw[p] & 0xffff0000u);
            sbv[2 * p]     = __uint_as_float(ubw[p] << 16);
            sbv[2 * p + 1] = __uint_as_float(ubw[p] & 0xffff0000u);
        }
#pragma unroll
        for (int u = 0; u < 8; ++u) {
            const float* w = Wc + (t + u) * COUT;   // wave-uniform -> s_load
#pragma unroll
            for (int j = 0; j < CA; ++j) acc[j] = fmaf(sav[u], w[j], acc[j]);
#pragma unroll
            for (int j = 0; j < CB; ++j)
                acc[CA + j] = fmaf(sbv[u], w[CA + j], acc[CA + j]);
        }
    }

    float impTot = impAcc[n];
    float denom  = impTot > 0.f ? impTot : 1.f;

    if (valid) {
        float res[COUT];
#pragma unroll
        for (int j = 0; j < CA; ++j) res[j] = fmaxf(acc[j] + ba[j], 0.f);
#pragma unroll
        for (int j = 0; j < CB; ++j)
            res[CA + j] = fmaxf(acc[CA + j] / denom + bb[j], 0.f);
        float4* op = reinterpret_cast<float4*>(outf + (size_t)n * COUT);
#pragma unroll
        for (int j4 = 0; j4 < 8; ++j4)
            op[j4] = make_float4(res[4 * j4], res[4 * j4 + 1],
                                 res[4 * j4 + 2], res[4 * j4 + 3]);
        outimp[n] = impTot;
    }
}

// ===========================================================================
// Fallback (round-6 fused kernel) if ws can't hold the scratch.
// ===========================================================================
static constexpr int WSTR = KC * CIN + 4;
static constexpr int PPB = 16;
static constexpr int TPB = 512;
static constexpr int NHW = TPB / 32;

__global__ void build_rowptr_fb(const int* __restrict__ oidx, int* __restrict__ rp,
                                int E, int nout) {
    int e = blockIdx.x * blockDim.x + threadIdx.x;
    if (e >= E) return;
    int cur  = oidx[e];
    int prev = (e == 0) ? -1 : oidx[e - 1];
    for (int id = prev + 1; id <= cur; ++id) rp[id] = e;
    if (e == E - 1) {
        for (int id = cur + 1; id <= nout; ++id) rp[id] = E;
    }
}

__global__ void pack_weights_fkc(const float* __restrict__ Wa,
                                 const float* __restrict__ Wb,
                                 float* __restrict__ Wt) {
    int t = blockIdx.x * blockDim.x + threadIdx.x;
    if (t >= COUT * KC * CIN) return;
    int f = t / (KC * CIN);
    int r = t % (KC * CIN);
    Wt[t] = (f < CA) ? Wa[r * CA + f] : Wb[r * CB + (f - CA)];
}

__global__ __launch_bounds__(TPB) void fused_block(
    const float* __restrict__ feats, const float* __restrict__ importance,
    const float* __restrict__ Wt, const float* __restrict__ ba,
    const float* __restrict__ bb,
    const int* __restrict__ nidx, const int* __restrict__ nkidx,
    const int* __restrict__ noidx, const int* __restrict__ rp,
    float* __restrict__ outf, float* __restrict__ outimp, int nout)
{
    __shared__ __align__(16) float sW[COUT * WSTR];
    __shared__ __align__(16) float sS[PPB][2][KC * CIN];
    __shared__ float sImp[PPB];

    const int tid = threadIdx.x;
    const int hw  = tid >> 5;
    const int c   = tid & 31;
    const int p0  = blockIdx.x * PPB;

    {
        float* pS = &sS[0][0][0];
        for (int i = tid; i < PPB * 2 * KC * CIN; i += TPB) pS[i] = 0.f;
        for (int i = tid; i < COUT * KC * CIN; i += TPB) {
            int f = i / (KC * CIN);
            int r = i % (KC * CIN);
            sW[f * WSTR + r] = Wt[i];
        }
        if (tid < PPB) sImp[tid] = 0.f;
    }
    __syncthreads();

    const int pend   = (p0 + PPB < nout) ? (p0 + PPB) : nout;
    const int estart = rp[p0];
    const int eend   = rp[pend];
    const int cnt    = eend - estart;
    const int per    = (cnt + NHW - 1) / NHW;
    int a = estart + hw * per;
    int b = a + per; if (b > eend) b = eend;

    float* S0 = &sS[0][0][0];
    for (int e = a; e < b; ++e) {
        int   n0 = noidx[e], i0 = nidx[e], q0 = nkidx[e];
        float m0 = importance[i0];
        float f0 = feats[(size_t)i0 * CIN + c];
        float* bp = S0 + (n0 - p0) * (2 * KC * CIN) + q0 * CIN + c;
        atomicAdd(bp, f0);
        atomicAdd(bp + KC * CIN, f0 * m0);
        if (c == 0) atomicAdd(&sImp[n0 - p0], m0);
    }
    __syncthreads();

    const int wave = tid >> 6;
    const int lane = tid & 63;
    const int f    = lane & 31;
    const int h    = lane >> 5;
#pragma unroll
    for (int rep = 0; rep < 2; ++rep) {
        const int slot = wave * 2 + rep;
        const int n    = p0 + slot;
        if (n >= nout) break;
        float impTot = sImp[slot];
        float denom  = impTot > 0.f ? impTot : 1.f;
        const float* Sbase = &sS[slot][(f < CA) ? 0 : 1][0];
        const float* Wbase = sW + f * WSTR;
        float acc = 0.f;
#pragma unroll
        for (int k = 0; k < KC; ++k) {
            int off = k * CIN + h * 16;
#pragma unroll
            for (int j = 0; j < 16; ++j) acc = fmaf(Sbase[off + j], Wbase[off + j], acc);
        }
        float tot = acc + __shfl_xor(acc, 32, 64);
        if (h == 0) {
            float res = (f < CA) ? (tot + ba[f]) : (tot / denom + bb[f - CA]);
            outf[(size_t)n * COUT + f] = fmaxf(res, 0.f);
        }
        if (lane == 0) outimp[n] = impTot;
    }
}

// ---------------------------------------------------------------------------
extern "C" void kernel_launch(void* const* d_in, const int* in_sizes, int n_in,
                              void* d_out, int out_size, void* d_ws, size_t ws_size,
                              hipStream_t stream) {
    const float* feats      = (const float*)d_in[0];
    const float* importance = (const float*)d_in[1];
    const float* Wa         = (const float*)d_in[2];
    const float* ba         = (const float*)d_in[3];
    const float* Wb         = (const float*)d_in[4];
    const float* bb         = (const float*)d_in[5];
    const int*   nidx       = (const int*)d_in[6];
    const int*   nkidx      = (const int*)d_in[7];
    const int*   noidx      = (const int*)d_in[8];

    const int E    = in_sizes[6];
    const int nout = out_size / (COUT + 1);

    float* outf   = (float*)d_out;
    float* outimp = outf + (size_t)nout * COUT;

    // ws: S bf16 [nout*576] | impAcc | Wc | rp | imp_e [E] | keym [E]
    const size_t off_imp = ((size_t)nout * SPP * sizeof(__hip_bfloat16) + 255) & ~(size_t)255;
    const size_t off_wc  = (off_imp + (size_t)nout * sizeof(float) + 255) & ~(size_t)255;
    const size_t off_rp  = (off_wc + (size_t)KCC * COUT * sizeof(float) + 255) & ~(size_t)255;
    const size_t off_ie  = (off_rp + (size_t)(nout + 1) * sizeof(int) + 255) & ~(size_t)255;
    const size_t off_km  = (off_ie + (size_t)E * sizeof(float) + 255) & ~(size_t)255;
    const size_t need    = off_km + (size_t)E * sizeof(int);

    if (ws_size >= need) {
        __hip_bfloat16* S = (__hip_bfloat16*)d_ws;
        float* impAcc = (float*)((char*)d_ws + off_imp);
        float* Wc     = (float*)((char*)d_ws + off_wc);
        int*   rp     = (int*)((char*)d_ws + off_rp);
        float* imp_e  = (float*)((char*)d_ws + off_ie);
        int*   keym   = (int*)((char*)d_ws + off_km);

        prep<<<(E + 255) / 256, 256, 0, stream>>>(
            noidx, nidx, nkidx, importance, Wa, Wb, rp, imp_e, keym, Wc, E, nout);
        accum_z<<<2048, 256, 0, stream>>>(
            feats, imp_e, keym, rp, S, impAcc, nout);
        epilogue_g<<<(nout + 255) / 256, 256, 0, stream>>>(
            S, impAcc, Wc, ba, bb, outf, outimp, nout);
    } else {
        int*   rp = (int*)d_ws;
        size_t rp_bytes = ((size_t)(nout + 1) * sizeof(int) + 255) & ~(size_t)255;
        float* Wt = (float*)((char*)d_ws + rp_bytes);

        build_rowptr_fb<<<(E + 255) / 256, 256, 0, stream>>>(noidx, rp, E, nout);
        pack_weights_fkc<<<(COUT * KC * CIN + 255) / 256, 256, 0, stream>>>(Wa, Wb, Wt);
        fused_block<<<(nout + PPB - 1) / PPB, TPB, 0, stream>>>(
            feats, importance, Wt, ba, bb, nidx, nkidx, noidx, rp,
            outf, outimp, nout);
    }
}